// Round 6
// baseline (812.467 us; speedup 1.0000x reference)
//
#include <hip/hip_runtime.h>
#include <hip/hip_bf16.h>
#include <stdint.h>

#define L1DIM 1536
#define NOUT  144           // 128 (W1) + 16 (Wf) layer-1 outputs
#define MTILE 16            // rows per block
#define NITER 6             // k-steps of 32 per wave (wave owns k-eighth = 192)

// ---- shared-memory word layout (4-B words, total 9464 = 37,856 B) ----
// [0..4223]      ep8[8][16][33]    (only ep8[0] = words 0..527 alive after reduce)
// [528..8239]    W2L: bf16x2 words, bkt*964 + loc*15 + j   (loc=0..63, j=0..14)
// [8240..8775]   WoL: fp32, bkt*67 + loc
// [8776..9311]   b2L: fp32, bkt*67 + loc
// [9312..9447]   b1L: fp32, bkt*17 + j
// [9448..9463]   bfL: fp32, j
#define W2L_OFF 528
#define WOL_OFF 8240
#define B2L_OFF 8776
#define B1L_OFF 9312
#define BFL_OFF 9448
#define SMW     9464

typedef __bf16 bf16;
typedef __bf16 bf16x8 __attribute__((ext_vector_type(8)));
typedef float  floatx4 __attribute__((ext_vector_type(4)));

// ---------------------------------------------------------------------------
// Pack [W1;Wf] (144 x 1536 fp32) -> bf16 in MFMA B-fragment order (unchanged).
// ---------------------------------------------------------------------------
__global__ __launch_bounds__(256) void pack_weights(
    const float* __restrict__ W1, const float* __restrict__ Wf,
    bf16* __restrict__ pw)
{
    int t = blockIdx.x * 256 + threadIdx.x;  // 0 .. 27647
    int n = t / 192;                         // output feature 0..143
    int o = t % 192;                         // k-octet 0..191
    const float* src = (n < 128) ? (W1 + (size_t)n * L1DIM + o * 8)
                                 : (Wf + (size_t)(n - 128) * L1DIM + o * 8);
    float4 s0 = ((const float4*)src)[0];
    float4 s1 = ((const float4*)src)[1];
    bf16x8 v;
    v[0] = (bf16)s0.x; v[1] = (bf16)s0.y; v[2] = (bf16)s0.z; v[3] = (bf16)s0.w;
    v[4] = (bf16)s1.x; v[5] = (bf16)s1.y; v[6] = (bf16)s1.z; v[7] = (bf16)s1.w;
    *(bf16x8*)(pw + ((size_t)o * NOUT + n) * 8) = v;
}

__device__ __forceinline__ bf16x8 cvt8(float4 a, float4 b) {
    bf16x8 r;
    r[0] = (bf16)a.x; r[1] = (bf16)a.y; r[2] = (bf16)a.z; r[3] = (bf16)a.w;
    r[4] = (bf16)b.x; r[5] = (bf16)b.y; r[6] = (bf16)b.z; r[7] = (bf16)b.w;
    return r;
}

__device__ __forceinline__ uint32_t pk_bf16(float a, float b) {
    union { __bf16 h[2]; uint32_t u; } r;
    r.h[0] = (__bf16)a; r.h[1] = (__bf16)b;
    return r.u;
}

// ---------------------------------------------------------------------------
// Main kernel: 512 threads = 8 waves = 8-way k-split (6 iters of 32 each).
// 4 blocks/CU x 8 waves = 32 waves/CU (100% occupancy); per-wave memory
// chain halved vs Round 5. K-loop math and LDS epilogue otherwise identical.
// ---------------------------------------------------------------------------
__global__ __launch_bounds__(512, 8) void layerstacks_main(
    const float* __restrict__ x, const int* __restrict__ lsidx,
    const bf16* __restrict__ pw,
    const float* __restrict__ b1, const float* __restrict__ bf_,
    const float* __restrict__ W2, const float* __restrict__ b2,
    const float* __restrict__ Wo, const float* __restrict__ bo,
    float* __restrict__ out)
{
    __shared__ uint32_t smu[SMW];
    float* sm = (float*)smu;

    const int tid  = threadIdx.x;
    const int wv   = tid >> 6;               // wave id == k-eighth, 0..7
    const int ln   = tid & 63;
    const int quad = ln >> 4;
    const int lm   = ln & 15;

    const int R0 = blockIdx.x * MTILE;

    const float* ax = x + (size_t)(R0 + lm) * L1DIM + wv * 192 + quad * 8;

    floatx4 acc[9];
#pragma unroll
    for (int i = 0; i < 9; i++) acc[i] = (floatx4){0.f, 0.f, 0.f, 0.f};

#pragma unroll
    for (int ki = 0; ki < NITER; ki++) {
        float4 a0 = *(const float4*)(ax + ki * 32);
        float4 a1 = *(const float4*)(ax + ki * 32 + 4);
        const bf16* bsl = pw + (size_t)(wv * 24 + ki * 4 + quad) * (NOUT * 8);
        bf16x8 af = cvt8(a0, a1);
#pragma unroll
        for (int t = 0; t < 9; t++) {
            bf16x8 bfr = *(const bf16x8*)(bsl + (size_t)(t * 16 + lm) * 8);
            acc[t] = __builtin_amdgcn_mfma_f32_16x16x32_bf16(af, bfr, acc[t], 0, 0, 0);
        }
    }

    // ---- per-wave bucket-gather (C layout: row = quad*4+r, col = lm) ----
#pragma unroll
    for (int r = 0; r < 4; r++) {
        const int row = quad * 4 + r;
        const int bkt = lsidx[R0 + row];
        float c = acc[0][r];
#pragma unroll
        for (int t = 1; t < 8; t++) c = (bkt == t) ? acc[t][r] : c;
        sm[wv * 528 + row * 33 + lm]      = c;
        sm[wv * 528 + row * 33 + 16 + lm] = acc[8][r];
    }
    __syncthreads();

    // ---- reduce the 8 k-eighth partials into ep8[0] (words 0..527) ----
    for (int w = tid; w < 528; w += 512) {
        float s = sm[w];
#pragma unroll
        for (int p = 1; p < 8; p++) s += sm[p * 528 + w];
        sm[w] = s;
    }
    __syncthreads();

    // ---- stage layer-2 operands into LDS (overlaps dead ep8[1..7]) ----
    for (int w = tid; w < 7680; w += 512) {
        const int oi = w / 15, j = w % 15;
        float2 s = *(const float2*)(W2 + (size_t)oi * 30 + 2 * j);
        smu[W2L_OFF + (oi >> 6) * 964 + (oi & 63) * 15 + j] = pk_bf16(s.x, s.y);
    }
    {
        const int b = tid >> 6, loc = tid & 63;   // tid<512 covers all 512
        sm[WOL_OFF + b * 67 + loc] = Wo[tid];
        sm[B2L_OFF + b * 67 + loc] = b2[tid];
    }
    if (tid < 128) sm[B1L_OFF + (tid >> 4) * 17 + (tid & 15)] = b1[tid];
    if (tid < 16)  sm[BFL_OFF + tid] = bf_[tid];
    __syncthreads();

    // ---- epilogue: 16 threads per row, each 4 output-features ----
    if (tid < 256) {
        const int er   = tid >> 4;
        const int s16  = tid & 15;
        const int grow = R0 + er;
        const int bkt  = lsidx[grow];

        const float* b1r = &sm[B1L_OFF + bkt * 17];
        const float l1c15 = sm[er * 33 + 15] + b1r[15];
        const float l1f15 = sm[er * 33 + 31] + sm[BFL_OFF + 15];

        float l1x[30];
#pragma unroll
        for (int j = 0; j < 15; j++) {
            float tj = (sm[er * 33 + j] + b1r[j])
                     + (sm[er * 33 + 16 + j] + sm[BFL_OFF + j]);
            float sq = tj * tj * (127.0f / 128.0f);
            l1x[j]      = fminf(fmaxf(sq, 0.f), 1.f);
            l1x[15 + j] = fminf(fmaxf(tj, 0.f), 1.f);
        }

        float part = 0.f;
#pragma unroll
        for (int o = 0; o < 4; o++) {
            const int loc = s16 + 16 * o;
            const uint32_t* wrow = &smu[W2L_OFF + bkt * 964 + loc * 15];
            float a = sm[B2L_OFF + bkt * 67 + loc];
#pragma unroll
            for (int j = 0; j < 15; j++) {
                union { uint32_t u; __bf16 h[2]; } c;
                c.u = wrow[j];
                a += l1x[2 * j] * (float)c.h[0] + l1x[2 * j + 1] * (float)c.h[1];
            }
            a = fminf(fmaxf(a, 0.f), 1.f);
            part += a * sm[WOL_OFF + bkt * 67 + loc];
        }
        part += __shfl_xor(part, 1);
        part += __shfl_xor(part, 2);
        part += __shfl_xor(part, 4);
        part += __shfl_xor(part, 8);
        if (s16 == 0) out[grow] = part + bo[bkt] + l1c15 + l1f15;
    }
}

// ---------------------------------------------------------------------------
// ABLATION 1: k-loop only, x4 reps (barriered apart), keep-alive to sink.
// Mirrors main's grid/block/occupancy. Duration/4 ~= k-loop share of main.
// ---------------------------------------------------------------------------
__global__ __launch_bounds__(512, 8) void abl_kloop(
    const float* __restrict__ x, const bf16* __restrict__ pw,
    float* __restrict__ sink)
{
    const int tid  = threadIdx.x;
    const int wv   = tid >> 6;
    const int ln   = tid & 63;
    const int quad = ln >> 4;
    const int lm   = ln & 15;

    floatx4 acc[9];
#pragma unroll
    for (int i = 0; i < 9; i++) acc[i] = (floatx4){0.f, 0.f, 0.f, 0.f};

#pragma unroll 1
    for (int rep = 0; rep < 4; rep++) {
        const int R0 = ((blockIdx.x ^ (rep * 311)) & 1023) * 16;
        const float* ax = x + (size_t)(R0 + lm) * L1DIM + wv * 192 + quad * 8;
#pragma unroll
        for (int ki = 0; ki < NITER; ki++) {
            float4 a0 = *(const float4*)(ax + ki * 32);
            float4 a1 = *(const float4*)(ax + ki * 32 + 4);
            const bf16* bsl = pw + (size_t)(wv * 24 + ki * 4 + quad) * (NOUT * 8);
            bf16x8 af = cvt8(a0, a1);
#pragma unroll
            for (int t = 0; t < 9; t++) {
                bf16x8 bfr = *(const bf16x8*)(bsl + (size_t)(t * 16 + lm) * 8);
                acc[t] = __builtin_amdgcn_mfma_f32_16x16x32_bf16(af, bfr, acc[t], 0, 0, 0);
            }
        }
        __syncthreads();   // serialize reps (honest per-rep chain)
    }
    float s = 0.f;
#pragma unroll
    for (int t = 0; t < 9; t++)
#pragma unroll
        for (int r = 0; r < 4; r++) s += acc[t][r];
    sink[(blockIdx.x * 512 + tid) & 0xFFFF] = s;
}

// ---------------------------------------------------------------------------
// ABLATION 2: epilogue only (synthetic ep values), stage once + compute x4.
// ---------------------------------------------------------------------------
__global__ __launch_bounds__(512, 8) void abl_epi(
    const int* __restrict__ lsidx,
    const float* __restrict__ b1, const float* __restrict__ bf_,
    const float* __restrict__ W2, const float* __restrict__ b2,
    const float* __restrict__ Wo, const float* __restrict__ bo,
    float* __restrict__ sink)
{
    __shared__ uint32_t smu[SMW];
    float* sm = (float*)smu;
    const int tid = threadIdx.x;

    for (int w = tid; w < 528; w += 512)
        sm[w] = (float)((w * 2654435761u) >> 24) * 0.004f - 0.5f;

    for (int w = tid; w < 7680; w += 512) {
        const int oi = w / 15, j = w % 15;
        float2 s = *(const float2*)(W2 + (size_t)oi * 30 + 2 * j);
        smu[W2L_OFF + (oi >> 6) * 964 + (oi & 63) * 15 + j] = pk_bf16(s.x, s.y);
    }
    {
        const int b = tid >> 6, loc = tid & 63;
        sm[WOL_OFF + b * 67 + loc] = Wo[tid];
        sm[B2L_OFF + b * 67 + loc] = b2[tid];
    }
    if (tid < 128) sm[B1L_OFF + (tid >> 4) * 17 + (tid & 15)] = b1[tid];
    if (tid < 16)  sm[BFL_OFF + tid] = bf_[tid];
    __syncthreads();

    float total = 0.f;
#pragma unroll 1
    for (int rep = 0; rep < 4; rep++) {
        if (tid < 256) {
            const int er   = ((tid >> 4) + rep * 5) & 15;
            const int s16  = tid & 15;
            const int grow = blockIdx.x * 16 + er;
            const int bkt  = lsidx[grow];

            const float* b1r = &sm[B1L_OFF + bkt * 17];
            float l1x[30];
#pragma unroll
            for (int j = 0; j < 15; j++) {
                float tj = (sm[er * 33 + j] + b1r[j])
                         + (sm[er * 33 + 16 + j] + sm[BFL_OFF + j]);
                float sq = tj * tj * (127.0f / 128.0f);
                l1x[j]      = fminf(fmaxf(sq, 0.f), 1.f);
                l1x[15 + j] = fminf(fmaxf(tj, 0.f), 1.f);
            }
            float part = 0.f;
#pragma unroll
            for (int o = 0; o < 4; o++) {
                const int loc = s16 + 16 * o;
                const uint32_t* wrow = &smu[W2L_OFF + bkt * 964 + loc * 15];
                float a = sm[B2L_OFF + bkt * 67 + loc];
#pragma unroll
                for (int j = 0; j < 15; j++) {
                    union { uint32_t u; __bf16 h[2]; } c;
                    c.u = wrow[j];
                    a += l1x[2 * j] * (float)c.h[0] + l1x[2 * j + 1] * (float)c.h[1];
                }
                a = fminf(fmaxf(a, 0.f), 1.f);
                part += a * sm[WOL_OFF + bkt * 67 + loc];
            }
            total += part + bo[bkt];
        }
        __syncthreads();   // serialize reps; uniform barrier (outside tid guard)
    }
    if (tid < 256) sink[(blockIdx.x * 256 + tid) & 0xFFFF] = total;
}

extern "C" void kernel_launch(void* const* d_in, const int* in_sizes, int n_in,
                              void* d_out, int out_size, void* d_ws, size_t ws_size,
                              hipStream_t stream) {
    const float* x   = (const float*)d_in[0];
    const int*   idx = (const int*)  d_in[1];
    const float* W1  = (const float*)d_in[2];
    const float* b1  = (const float*)d_in[3];
    const float* Wf  = (const float*)d_in[4];
    const float* bf  = (const float*)d_in[5];
    const float* W2  = (const float*)d_in[6];
    const float* b2  = (const float*)d_in[7];
    const float* Wo  = (const float*)d_in[8];
    const float* bo  = (const float*)d_in[9];
    float* out = (float*)d_out;
    bf16*  pw  = (bf16*)d_ws;                 // 442368 B of workspace
    float* sink = (float*)d_ws;               // ablation keep-alive (clobbers pw
                                              // AFTER main has consumed it)

    pack_weights<<<dim3(108), dim3(256), 0, stream>>>(W1, Wf, pw);
    layerstacks_main<<<dim3(16384 / MTILE), dim3(512), 0, stream>>>(
        x, idx, pw, b1, bf, W2, b2, Wo, bo, out);
    // ---- diagnostic ablations (write only into workspace; out already final)
    abl_kloop<<<dim3(1024), dim3(512), 0, stream>>>(x, pw, sink);
    abl_epi  <<<dim3(1024), dim3(512), 0, stream>>>(idx, b1, bf, W2, b2, Wo, bo, sink);
}

// Round 7
// 195.896 us; speedup vs baseline: 4.1474x; 4.1474x over previous
//
#include <hip/hip_runtime.h>
#include <hip/hip_bf16.h>
#include <stdint.h>

#define L1DIM 1536
#define NOUT  144           // 128 (W1) + 16 (Wf) layer-1 outputs
#define MTILE 16            // rows per block
#define NITER 12            // k-steps of 32 per wave (wave owns k-quarter = 384)

// ---- shared-memory word layout (4-B words, total 9464 = 37,856 B) ----
// [0..2111]      ep4[4][16][33]    (only ep4[0] = words 0..527 alive after reduce)
// [528..8239]    W2L: bf16x2 words, bkt*964 + loc*15 + j   (loc=0..63, j=0..14)
// [8240..8775]   WoL: fp32, bkt*67 + loc
// [8776..9311]   b2L: fp32, bkt*67 + loc
// [9312..9447]   b1L: fp32, bkt*17 + j
// [9448..9463]   bfL: fp32, j
#define W2L_OFF 528
#define WOL_OFF 8240
#define B2L_OFF 8776
#define B1L_OFF 9312
#define BFL_OFF 9448
#define SMW     9464

typedef __bf16 bf16;
typedef __bf16 bf16x8 __attribute__((ext_vector_type(8)));
typedef float  floatx4 __attribute__((ext_vector_type(4)));

// ---------------------------------------------------------------------------
// Pack [W1;Wf] (144 x 1536 fp32) -> bf16 in MFMA B-fragment order (unchanged).
// ---------------------------------------------------------------------------
__global__ __launch_bounds__(256) void pack_weights(
    const float* __restrict__ W1, const float* __restrict__ Wf,
    bf16* __restrict__ pw)
{
    int t = blockIdx.x * 256 + threadIdx.x;  // 0 .. 27647
    int n = t / 192;                         // output feature 0..143
    int o = t % 192;                         // k-octet 0..191
    const float* src = (n < 128) ? (W1 + (size_t)n * L1DIM + o * 8)
                                 : (Wf + (size_t)(n - 128) * L1DIM + o * 8);
    float4 s0 = ((const float4*)src)[0];
    float4 s1 = ((const float4*)src)[1];
    bf16x8 v;
    v[0] = (bf16)s0.x; v[1] = (bf16)s0.y; v[2] = (bf16)s0.z; v[3] = (bf16)s0.w;
    v[4] = (bf16)s1.x; v[5] = (bf16)s1.y; v[6] = (bf16)s1.z; v[7] = (bf16)s1.w;
    *(bf16x8*)(pw + ((size_t)o * NOUT + n) * 8) = v;
}

__device__ __forceinline__ bf16x8 cvt8(float4 a, float4 b) {
    bf16x8 r;
    r[0] = (bf16)a.x; r[1] = (bf16)a.y; r[2] = (bf16)a.z; r[3] = (bf16)a.w;
    r[4] = (bf16)b.x; r[5] = (bf16)b.y; r[6] = (bf16)b.z; r[7] = (bf16)b.w;
    return r;
}

__device__ __forceinline__ uint32_t pk_bf16(float a, float b) {
    union { __bf16 h[2]; uint32_t u; } r;
    r.h[0] = (__bf16)a; r.h[1] = (__bf16)b;
    return r.u;
}

// liveness pin: force the loaded value to exist at this program point
// (prevents the compiler from sinking the load into the next iteration)
#define KEEP4(v_)  asm volatile("" :: "v"(__builtin_bit_cast(floatx4, v_)))

// ---------------------------------------------------------------------------
// Main kernel. Geometry identical to Round 5 (MTILE=16, 4 waves, 4-way
// k-split, LDS epilogue). ONE change: the k-loop is explicitly register
// double-buffered -- all 11 loads of iteration ki+1 (2 A-frags + 9 B-frags)
// are issued into a second register slot BEFORE the 9 MFMAs of iteration ki,
// and pinned live at the end of the iteration. This forces ~11 loads in
// flight per wave (R5's VGPR_Count=52 showed the compiler kept only ~3).
// __launch_bounds__(256,3): 12 waves/CU, VGPR cap ~168 -- room for the
// ~150-reg pipeline without spill (Round 6 lesson: never cap below live set).
// ---------------------------------------------------------------------------
__global__ __launch_bounds__(256, 3) void layerstacks_main(
    const float* __restrict__ x, const int* __restrict__ lsidx,
    const bf16* __restrict__ pw,
    const float* __restrict__ b1, const float* __restrict__ bf_,
    const float* __restrict__ W2, const float* __restrict__ b2,
    const float* __restrict__ Wo, const float* __restrict__ bo,
    float* __restrict__ out)
{
    __shared__ uint32_t smu[SMW];
    float* sm = (float*)smu;

    const int tid  = threadIdx.x;
    const int wv   = tid >> 6;               // wave id == k-quarter
    const int ln   = tid & 63;
    const int quad = ln >> 4;
    const int lm   = ln & 15;

    const int R0 = blockIdx.x * MTILE;

    const float* ax = x + (size_t)(R0 + lm) * L1DIM + wv * 384 + quad * 8;

    floatx4 acc[9];
#pragma unroll
    for (int i = 0; i < 9; i++) acc[i] = (floatx4){0.f, 0.f, 0.f, 0.f};

    // ---- register-double-buffered k-loop ----
    float4  pa0[2], pa1[2];
    bf16x8  bb[2][9];

#define LOADS(slot_, ki_)                                                     \
    {                                                                         \
        pa0[slot_] = *(const float4*)(ax + (ki_) * 32);                       \
        pa1[slot_] = *(const float4*)(ax + (ki_) * 32 + 4);                   \
        const bf16* bsl = pw + (size_t)(wv * 48 + (ki_) * 4 + quad) * (NOUT * 8); \
        _Pragma("unroll")                                                     \
        for (int t = 0; t < 9; t++)                                           \
            bb[slot_][t] = *(const bf16x8*)(bsl + (size_t)(t * 16 + lm) * 8); \
    }

    LOADS(0, 0)

#pragma unroll
    for (int ki = 0; ki < NITER; ki++) {
        const int cur = ki & 1;
        const int nxt = cur ^ 1;
        if (ki < NITER - 1) LOADS(nxt, ki + 1)

        bf16x8 af = cvt8(pa0[cur], pa1[cur]);
#pragma unroll
        for (int t = 0; t < 9; t++)
            acc[t] = __builtin_amdgcn_mfma_f32_16x16x32_bf16(af, bb[cur][t], acc[t], 0, 0, 0);

        if (ki < NITER - 1) {
            // pin next-slot values live here: loads may not sink below this
            KEEP4(pa0[nxt]); KEEP4(pa1[nxt]);
#pragma unroll
            for (int t = 0; t < 9; t++) KEEP4(bb[nxt][t]);
        }
    }
#undef LOADS

    // ---- per-wave bucket-gather (C layout: row = quad*4+r, col = lm) ----
#pragma unroll
    for (int r = 0; r < 4; r++) {
        const int row = quad * 4 + r;
        const int bkt = lsidx[R0 + row];
        float c = acc[0][r];
#pragma unroll
        for (int t = 1; t < 8; t++) c = (bkt == t) ? acc[t][r] : c;
        sm[wv * 528 + row * 33 + lm]      = c;
        sm[wv * 528 + row * 33 + 16 + lm] = acc[8][r];
    }
    __syncthreads();

    // ---- reduce the 4 k-quarter partials into ep4[0] (words 0..527) ----
    {
        const int col = tid & 31;
        const int rr  = tid >> 5;            // 0..7
#pragma unroll
        for (int p = 0; p < 2; p++) {
            const int row = rr + p * 8;
            sm[row * 33 + col] = sm[row * 33 + col] + sm[528 + row * 33 + col]
                               + sm[1056 + row * 33 + col] + sm[1584 + row * 33 + col];
        }
    }
    __syncthreads();

    // ---- stage layer-2 operands into LDS (overlaps dead ep4[1..3]) ----
    for (int w = tid; w < 7680; w += 256) {
        const int oi = w / 15, j = w % 15;
        float2 s = *(const float2*)(W2 + (size_t)oi * 30 + 2 * j);
        smu[W2L_OFF + (oi >> 6) * 964 + (oi & 63) * 15 + j] = pk_bf16(s.x, s.y);
    }
    for (int i = tid; i < 512; i += 256) {
        const int b = i >> 6, loc = i & 63;
        sm[WOL_OFF + b * 67 + loc] = Wo[i];
        sm[B2L_OFF + b * 67 + loc] = b2[i];
    }
    if (tid < 128) sm[B1L_OFF + (tid >> 4) * 17 + (tid & 15)] = b1[tid];
    if (tid < 16)  sm[BFL_OFF + tid] = bf_[tid];
    __syncthreads();

    // ---- epilogue: 16 threads per row, each 4 output-features ----
    {
        const int er   = tid >> 4;           // row in tile, 0..15
        const int s16  = tid & 15;
        const int grow = R0 + er;
        const int bkt  = lsidx[grow];

        const float* b1r = &sm[B1L_OFF + bkt * 17];
        const float l1c15 = sm[er * 33 + 15] + b1r[15];
        const float l1f15 = sm[er * 33 + 31] + sm[BFL_OFF + 15];

        float l1x[30];
#pragma unroll
        for (int j = 0; j < 15; j++) {
            float tj = (sm[er * 33 + j] + b1r[j])
                     + (sm[er * 33 + 16 + j] + sm[BFL_OFF + j]);
            float sq = tj * tj * (127.0f / 128.0f);
            l1x[j]      = fminf(fmaxf(sq, 0.f), 1.f);
            l1x[15 + j] = fminf(fmaxf(tj, 0.f), 1.f);
        }

        float part = 0.f;
#pragma unroll
        for (int o = 0; o < 4; o++) {
            const int loc = s16 + 16 * o;
            const uint32_t* wrow = &smu[W2L_OFF + bkt * 964 + loc * 15];
            float a = sm[B2L_OFF + bkt * 67 + loc];
#pragma unroll
            for (int j = 0; j < 15; j++) {
                union { uint32_t u; __bf16 h[2]; } c;
                c.u = wrow[j];
                a += l1x[2 * j] * (float)c.h[0] + l1x[2 * j + 1] * (float)c.h[1];
            }
            a = fminf(fmaxf(a, 0.f), 1.f);
            part += a * sm[WOL_OFF + bkt * 67 + loc];
        }
        part += __shfl_xor(part, 1);
        part += __shfl_xor(part, 2);
        part += __shfl_xor(part, 4);
        part += __shfl_xor(part, 8);
        if (s16 == 0) out[grow] = part + bo[bkt] + l1c15 + l1f15;
    }
}

extern "C" void kernel_launch(void* const* d_in, const int* in_sizes, int n_in,
                              void* d_out, int out_size, void* d_ws, size_t ws_size,
                              hipStream_t stream) {
    const float* x   = (const float*)d_in[0];
    const int*   idx = (const int*)  d_in[1];
    const float* W1  = (const float*)d_in[2];
    const float* b1  = (const float*)d_in[3];
    const float* Wf  = (const float*)d_in[4];
    const float* bf  = (const float*)d_in[5];
    const float* W2  = (const float*)d_in[6];
    const float* b2  = (const float*)d_in[7];
    const float* Wo  = (const float*)d_in[8];
    const float* bo  = (const float*)d_in[9];
    float* out = (float*)d_out;
    bf16*  pw  = (bf16*)d_ws;                 // 442368 B of workspace

    pack_weights<<<dim3(108), dim3(256), 0, stream>>>(W1, Wf, pw);
    layerstacks_main<<<dim3(16384 / MTILE), dim3(256), 0, stream>>>(
        x, idx, pw, b1, bf, W2, b2, Wo, bo, out);
}

// Round 8
// 184.901 us; speedup vs baseline: 4.3941x; 1.0595x over previous
//
#include <hip/hip_runtime.h>
#include <hip/hip_bf16.h>
#include <stdint.h>

#define L1DIM 1536
#define NOUT  144           // 128 (W1) + 16 (Wf) layer-1 outputs
#define MTILE 16            // rows per block
#define NITER 12            // k-steps of 32 per wave (wave owns k-quarter = 384)
#define WIN   128           // local-sort window (8 slices of 16 rows)

// ---- shared-memory word layout (4-B words) ----
// [0..2111]      ep4[4][16][33]    (only ep4[0] alive after reduce)
// [528..8239]    W2L: bf16x2 words, bkt*964 + loc*15 + j
// [8240..8775]   WoL: fp32, bkt*67 + loc
// [8776..9311]   b2L: fp32, bkt*67 + loc
// [9312..9447]   b1L: fp32, bkt*17 + j
// [9448..9463]   bfL: fp32, j
// [9464..9591]   skeys[128]  (window bucket keys; sorted after phase 2)
// [9592..9719]   sperm[128]  (sorted global row ids)
#define W2L_OFF 528
#define WOL_OFF 8240
#define B2L_OFF 8776
#define B1L_OFF 9312
#define BFL_OFF 9448
#define SKY_OFF 9464
#define SPM_OFF 9592
#define SMW     9720        // 38,880 B -> 4 blocks/CU (155.5 KB of 160)

typedef __bf16 bf16;
typedef __bf16 bf16x8 __attribute__((ext_vector_type(8)));
typedef float  floatx4 __attribute__((ext_vector_type(4)));

// ---------------------------------------------------------------------------
// Pack [W1;Wf] (144 x 1536 fp32) -> bf16 in MFMA B-fragment order (unchanged).
// ---------------------------------------------------------------------------
__global__ __launch_bounds__(256) void pack_weights(
    const float* __restrict__ W1, const float* __restrict__ Wf,
    bf16* __restrict__ pw)
{
    int t = blockIdx.x * 256 + threadIdx.x;  // 0 .. 27647
    int n = t / 192;                         // output feature 0..143
    int o = t % 192;                         // k-octet 0..191
    const float* src = (n < 128) ? (W1 + (size_t)n * L1DIM + o * 8)
                                 : (Wf + (size_t)(n - 128) * L1DIM + o * 8);
    float4 s0 = ((const float4*)src)[0];
    float4 s1 = ((const float4*)src)[1];
    bf16x8 v;
    v[0] = (bf16)s0.x; v[1] = (bf16)s0.y; v[2] = (bf16)s0.z; v[3] = (bf16)s0.w;
    v[4] = (bf16)s1.x; v[5] = (bf16)s1.y; v[6] = (bf16)s1.z; v[7] = (bf16)s1.w;
    *(bf16x8*)(pw + ((size_t)o * NOUT + n) * 8) = v;
}

__device__ __forceinline__ bf16x8 cvt8(float4 a, float4 b) {
    bf16x8 r;
    r[0] = (bf16)a.x; r[1] = (bf16)a.y; r[2] = (bf16)a.z; r[3] = (bf16)a.w;
    r[4] = (bf16)b.x; r[5] = (bf16)b.y; r[6] = (bf16)b.z; r[7] = (bf16)b.w;
    return r;
}

__device__ __forceinline__ uint32_t pk_bf16(float a, float b) {
    union { __bf16 h[2]; uint32_t u; } r;
    r.h[0] = (__bf16)a; r.h[1] = (__bf16)b;
    return r.u;
}

// ---------------------------------------------------------------------------
// Main kernel == Round 5 plus ONE change: windowed local bucket-sort.
// Block (win = bid>>3, slice = bid&7) sorts its 128-row window's bucket keys
// in LDS, takes sorted rows [slice*16, slice*16+16), and computes a
// wave-uniform bitmask of buckets present in its 16 rows. The k-loop then
// loads + MFMAs ONLY the needed B-tiles (~2 buckets + Wf instead of 9),
// cutting the dominant L2 traffic term (B: 442 MB grid-wide) by ~3x.
// ---------------------------------------------------------------------------
__global__ __launch_bounds__(256, 4) void layerstacks_main(
    const float* __restrict__ x, const int* __restrict__ lsidx,
    const bf16* __restrict__ pw,
    const float* __restrict__ b1, const float* __restrict__ bf_,
    const float* __restrict__ W2, const float* __restrict__ b2,
    const float* __restrict__ Wo, const float* __restrict__ bo,
    float* __restrict__ out)
{
    __shared__ uint32_t smu[SMW];
    float* sm    = (float*)smu;
    int*   skeys = (int*)&smu[SKY_OFF];
    int*   sperm = (int*)&smu[SPM_OFF];

    const int tid  = threadIdx.x;
    const int wv   = tid >> 6;               // wave id == k-quarter
    const int ln   = tid & 63;
    const int quad = ln >> 4;
    const int lm   = ln & 15;

    const int win   = blockIdx.x >> 3;       // 128-row window id
    const int slice = blockIdx.x & 7;        // 16-row slice within window
    const int base  = win * WIN;

    // ---- phase 1: load window keys ----
    if (tid < WIN) skeys[tid] = lsidx[base + tid];
    __syncthreads();

    // ---- phase 2: O(N^2) stable rank sort (128 threads, ~0.3 us) ----
    if (tid < WIN) {
        const int key = skeys[tid];
        int rank = 0;
        for (int j = 0; j < WIN; j++) {
            const int kj = skeys[j];
            rank += (kj < key) | ((kj == key) & (j < tid));
        }
        sperm[rank] = base + tid;            // sorted global row id
    }
    __syncthreads();
    if (tid < WIN) skeys[tid] = lsidx[sperm[tid]];   // sorted keys (L1-hot)
    __syncthreads();

    // ---- wave-uniform needed-bucket mask for this slice ----
    int nm = 0;
#pragma unroll
    for (int r = 0; r < 16; r++) nm |= 1 << skeys[slice * 16 + r];
    nm = __builtin_amdgcn_readfirstlane(nm);

    const int myrow = sperm[slice * 16 + lm];        // this lane's A row

    const float* ax = x + (size_t)myrow * L1DIM + wv * 384 + quad * 8;

    floatx4 acc[9];
#pragma unroll
    for (int i = 0; i < 9; i++) acc[i] = (floatx4){0.f, 0.f, 0.f, 0.f};

#pragma unroll
    for (int ki = 0; ki < NITER; ki++) {
        float4 a0 = *(const float4*)(ax + ki * 32);
        float4 a1 = *(const float4*)(ax + ki * 32 + 4);
        const bf16* bsl = pw + (size_t)(wv * 48 + ki * 4 + quad) * (NOUT * 8);
        bf16x8 af = cvt8(a0, a1);
#pragma unroll
        for (int t = 0; t < 9; t++) {
            if (t == 8 || ((nm >> t) & 1)) {         // scalar-branch skip
                bf16x8 bfr = *(const bf16x8*)(bsl + (size_t)(t * 16 + lm) * 8);
                acc[t] = __builtin_amdgcn_mfma_f32_16x16x32_bf16(af, bfr, acc[t], 0, 0, 0);
            }
        }
    }

    // ---- per-wave bucket-gather (C layout: row = quad*4+r, col = lm) ----
#pragma unroll
    for (int r = 0; r < 4; r++) {
        const int row = quad * 4 + r;
        const int bkt = skeys[slice * 16 + row];
        float c = acc[0][r];
#pragma unroll
        for (int t = 1; t < 8; t++) c = (bkt == t) ? acc[t][r] : c;
        sm[wv * 528 + row * 33 + lm]      = c;
        sm[wv * 528 + row * 33 + 16 + lm] = acc[8][r];
    }
    __syncthreads();

    // ---- reduce the 4 k-quarter partials into ep4[0] (words 0..527) ----
    {
        const int col = tid & 31;
        const int rr  = tid >> 5;            // 0..7
#pragma unroll
        for (int p = 0; p < 2; p++) {
            const int row = rr + p * 8;
            sm[row * 33 + col] = sm[row * 33 + col] + sm[528 + row * 33 + col]
                               + sm[1056 + row * 33 + col] + sm[1584 + row * 33 + col];
        }
    }
    __syncthreads();

    // ---- stage layer-2 operands into LDS (overlaps dead ep4[1..3]) ----
    for (int w = tid; w < 7680; w += 256) {
        const int oi = w / 15, j = w % 15;
        float2 s = *(const float2*)(W2 + (size_t)oi * 30 + 2 * j);
        smu[W2L_OFF + (oi >> 6) * 964 + (oi & 63) * 15 + j] = pk_bf16(s.x, s.y);
    }
    for (int i = tid; i < 512; i += 256) {
        const int b = i >> 6, loc = i & 63;
        sm[WOL_OFF + b * 67 + loc] = Wo[i];
        sm[B2L_OFF + b * 67 + loc] = b2[i];
    }
    if (tid < 128) sm[B1L_OFF + (tid >> 4) * 17 + (tid & 15)] = b1[tid];
    if (tid < 16)  sm[BFL_OFF + tid] = bf_[tid];
    __syncthreads();

    // ---- epilogue: 16 threads per row, each 4 output-features ----
    {
        const int er   = tid >> 4;           // row in tile, 0..15
        const int s16  = tid & 15;
        const int grow = sperm[slice * 16 + er];
        const int bkt  = skeys[slice * 16 + er];

        const float* b1r = &sm[B1L_OFF + bkt * 17];
        const float l1c15 = sm[er * 33 + 15] + b1r[15];
        const float l1f15 = sm[er * 33 + 31] + sm[BFL_OFF + 15];

        float l1x[30];
#pragma unroll
        for (int j = 0; j < 15; j++) {
            float tj = (sm[er * 33 + j] + b1r[j])
                     + (sm[er * 33 + 16 + j] + sm[BFL_OFF + j]);
            float sq = tj * tj * (127.0f / 128.0f);
            l1x[j]      = fminf(fmaxf(sq, 0.f), 1.f);
            l1x[15 + j] = fminf(fmaxf(tj, 0.f), 1.f);
        }

        float part = 0.f;
#pragma unroll
        for (int o = 0; o < 4; o++) {
            const int loc = s16 + 16 * o;
            const uint32_t* wrow = &smu[W2L_OFF + bkt * 964 + loc * 15];
            float a = sm[B2L_OFF + bkt * 67 + loc];
#pragma unroll
            for (int j = 0; j < 15; j++) {
                union { uint32_t u; __bf16 h[2]; } c;
                c.u = wrow[j];
                a += l1x[2 * j] * (float)c.h[0] + l1x[2 * j + 1] * (float)c.h[1];
            }
            a = fminf(fmaxf(a, 0.f), 1.f);
            part += a * sm[WOL_OFF + bkt * 67 + loc];
        }
        part += __shfl_xor(part, 1);
        part += __shfl_xor(part, 2);
        part += __shfl_xor(part, 4);
        part += __shfl_xor(part, 8);
        if (s16 == 0) out[grow] = part + bo[bkt] + l1c15 + l1f15;
    }
}

extern "C" void kernel_launch(void* const* d_in, const int* in_sizes, int n_in,
                              void* d_out, int out_size, void* d_ws, size_t ws_size,
                              hipStream_t stream) {
    const float* x   = (const float*)d_in[0];
    const int*   idx = (const int*)  d_in[1];
    const float* W1  = (const float*)d_in[2];
    const float* b1  = (const float*)d_in[3];
    const float* Wf  = (const float*)d_in[4];
    const float* bf  = (const float*)d_in[5];
    const float* W2  = (const float*)d_in[6];
    const float* b2  = (const float*)d_in[7];
    const float* Wo  = (const float*)d_in[8];
    const float* bo  = (const float*)d_in[9];
    float* out = (float*)d_out;
    bf16*  pw  = (bf16*)d_ws;                 // 442368 B of workspace

    pack_weights<<<dim3(108), dim3(256), 0, stream>>>(W1, Wf, pw);
    layerstacks_main<<<dim3(16384 / MTILE), dim3(256), 0, stream>>>(
        x, idx, pw, b1, bf, W2, b2, Wo, bo, out);
}